// Round 3
// baseline (216.710 us; speedup 1.0000x reference)
//
#include <hip/hip_runtime.h>
#include <hip/hip_bf16.h>
#include <cstdint>
#include <cstddef>

typedef __bf16 bf16_t;
typedef __bf16 bf16x8 __attribute__((ext_vector_type(8)));
typedef __bf16 bf16x4 __attribute__((ext_vector_type(4)));
typedef float f32x4 __attribute__((ext_vector_type(4)));

#define DM 1024
#define NHEAD 16
#define DHEAD 64

// Q scale folded into projection: 1/sqrt(64) * log2(e)
#define QSCALE 0.18033688011112042f
// fixed exp2 shift (cancels exactly in O/l)
#define PSHIFT 4.0f
// padded LDS row stride for attention tiles
#define RS 72

// counted vmcnt: lets N loads stay in flight across a raw barrier (T4)
#define WAITVM(N) asm volatile("s_waitcnt vmcnt(" #N ")" ::: "memory")

__device__ __forceinline__ void gload_lds16(const void* g, void* l) {
    __builtin_amdgcn_global_load_lds(
        (const __attribute__((address_space(1))) void*)g,
        (__attribute__((address_space(3))) void*)l,
        16, 0, 0);
}

__device__ __forceinline__ uint4 cvt8(float4 lo, float4 hi) {
    union { bf16_t b[8]; uint4 u; } o;
    o.b[0] = (bf16_t)lo.x; o.b[1] = (bf16_t)lo.y; o.b[2] = (bf16_t)lo.z; o.b[3] = (bf16_t)lo.w;
    o.b[4] = (bf16_t)hi.x; o.b[5] = (bf16_t)hi.y; o.b[6] = (bf16_t)hi.z; o.b[7] = (bf16_t)hi.w;
    return o.u;
}

// ---------------- prep: fused cast(3 tensors) + transpose(4 weights) ---------
// blocks [0, 6144): cast plane id>>11, 8 elem/thread.
// blocks [6144, 7168): W transpose, matrix (id-6144)>>8, 64x64 tile.
__global__ void prep(
    const float* __restrict__ q_in, const float* __restrict__ k_in, const float* __restrict__ v_in,
    bf16_t* __restrict__ Xq, bf16_t* __restrict__ Xk, bf16_t* __restrict__ Xv,
    const float* __restrict__ w0, const float* __restrict__ w1,
    const float* __restrict__ w2, const float* __restrict__ w3,
    bf16_t* __restrict__ t0, bf16_t* __restrict__ t1,
    bf16_t* __restrict__ t2, bf16_t* __restrict__ t3)
{
    __shared__ float tile[64][65];
    int id = blockIdx.x;
    if (id < 6144) {
        int plane = id >> 11;
        int blk = id & 2047;
        const float* x = plane == 0 ? q_in : plane == 1 ? k_in : v_in;
        bf16_t* y      = plane == 0 ? Xq   : plane == 1 ? Xk   : Xv;
        int i = (blk * 256 + threadIdx.x) * 8;
        float4 lo = *(const float4*)&x[i];
        float4 hi = *(const float4*)&x[i + 4];
        *(uint4*)&y[i] = cvt8(lo, hi);
    } else {
        int t = id - 6144;
        int zi = t >> 8;
        int blk = t & 255;
        const float* w = zi == 0 ? w0 : zi == 1 ? w1 : zi == 2 ? w2 : w3;
        bf16_t* wt     = zi == 0 ? t0 : zi == 1 ? t1 : zi == 2 ? t2 : t3;
        int bx = (blk & 15) * 64;    // n base
        int by = (blk >> 4) * 64;    // k base
        int tx = threadIdx.x & 63, ty = threadIdx.x >> 6;   // 64 x 4
        for (int j = 0; j < 64; j += 4)
            tile[ty + j][tx] = w[(size_t)(by + ty + j) * DM + bx + tx];
        __syncthreads();
        int nl = threadIdx.x >> 3;           // 0..31
        int kl = (threadIdx.x & 7) * 8;      // 0..56
        for (int j = 0; j < 64; j += 32) {
            int n = nl + j;
            union { bf16_t b[8]; uint4 u; } o;
            for (int i = 0; i < 8; i++)
                o.b[i] = (bf16_t)tile[kl + i][n];
            *(uint4*)&wt[(size_t)(bx + n) * DM + by + kl] = o.u;
        }
    }
}

// ---------------- GEMM core: 128x128 tile, BK=32, 4-slot ring, depth-3 ------
// T4 pipeline: 4 LDS ring slots, prefetch distance 3. Per step: wait vmcnt(8)
// (retires ONLY the oldest step's 4 loads; 8 stay in flight across the raw
// s_barrier), barrier, issue stage(t+3) into the slot whose readers the
// barrier just closed, compute step t. Load latency (~200-900cy) now spans
// 3 compute steps instead of 1.
// MODE 1: bf16 out [bh][s][d], v=(acc+bias[C])*scale
// MODE 2: bf16 out Vt [bh][d][s], R=channel, C=token, v=acc+bias[R]
template <int MODE>
__device__ __forceinline__ void gemm_body(
    const bf16_t* __restrict__ A, const bf16_t* __restrict__ Bt,
    const float* __restrict__ bias, float scale,
    bf16_t* __restrict__ Cb,
    int r0, int c0, bf16_t* AsP, bf16_t* BsP)
{
    const int K = 1024;
    int tid  = threadIdx.x;
    int wave = tid >> 6;
    int lane = tid & 63;
    int quad = lane >> 4;
    int ln   = lane & 15;
    int wr   = wave >> 1;
    int wc   = wave & 1;

    f32x4 acc[4][4];
    for (int rb = 0; rb < 4; rb++)
        for (int cb = 0; cb < 4; cb++)
            acc[rb][cb] = (f32x4){0.f, 0.f, 0.f, 0.f};

    int sr = tid >> 2;
    int sk = (tid & 3) * 8;

    const bf16_t* gA0 = &A[(size_t)(r0 + sr) * K + sk];
    const bf16_t* gA1 = gA0 + (size_t)64 * K;
    const bf16_t* gB0 = &Bt[(size_t)(c0 + sr) * K + sk];
    const bf16_t* gB1 = gB0 + (size_t)64 * K;
    char* lA = (char*)AsP + wave * 1024;   // ring slot stride 8192 B
    char* lB = (char*)BsP + wave * 1024;

    auto STAGE = [&](int s) {
        int off = (s & 3) * 8192;
        int k = s * 32;
        gload_lds16(gA0 + k, lA + off);
        gload_lds16(gA1 + k, lA + off + 4096);
        gload_lds16(gB0 + k, lB + off);
        gload_lds16(gB1 + k, lB + off + 4096);
    };
    auto COMPUTE = [&](int t) {
        const bf16_t* Ab = AsP + (t & 3) * 4096;   // 4096 bf16 = 8 KB slot
        const bf16_t* Bb = BsP + (t & 3) * 4096;
        bf16x8 af[4], bfv[4];
        for (int rb = 0; rb < 4; rb++)
            af[rb] = *(const bf16x8*)&Ab[(wr * 64 + rb * 16 + ln) * 32 + quad * 8];
        for (int cb = 0; cb < 4; cb++)
            bfv[cb] = *(const bf16x8*)&Bb[(wc * 64 + cb * 16 + ln) * 32 + quad * 8];
        for (int rb = 0; rb < 4; rb++)
            for (int cb = 0; cb < 4; cb++)
                acc[rb][cb] = __builtin_amdgcn_mfma_f32_16x16x32_bf16(af[rb], bfv[cb], acc[rb][cb], 0, 0, 0);
    };

    STAGE(0); STAGE(1); STAGE(2);

    // main: 29 iters with stage(t+3); outstanding at top = 12, wait(8) retires step t
    for (int t = 0; t < 29; ++t) {
        WAITVM(8);
        __builtin_amdgcn_s_barrier();
        STAGE(t + 3);
        COMPUTE(t);
    }
    // drain: outstanding 12 -> 8 -> 4
    WAITVM(8); __builtin_amdgcn_s_barrier(); COMPUTE(29);
    WAITVM(4); __builtin_amdgcn_s_barrier(); COMPUTE(30);
    WAITVM(0); __builtin_amdgcn_s_barrier(); COMPUTE(31);

    for (int rb = 0; rb < 4; rb++) {
        for (int cb = 0; cb < 4; cb++) {
            int C = c0 + wc * 64 + cb * 16 + ln;
            for (int r = 0; r < 4; r++) {
                int R = r0 + wr * 64 + rb * 16 + quad * 4 + r;
                float v = acc[rb][cb][r];
                if (MODE == 1) {
                    int b = R >> 10, s = R & 1023;
                    int h = C >> 6,  d = C & 63;
                    Cb[(((size_t)b * NHEAD + h) * 1024 + s) * DHEAD + d] =
                        (bf16_t)((v + bias[C]) * scale);
                } else {
                    Cb[((size_t)(C >> 10) * 1024 + R) * 1024 + (C & 1023)] =
                        (bf16_t)(v + bias[R]);
                }
            }
        }
    }
}

// grid (32, 8, 3): x = M-tile (XCD locality: id%8 = x%8), y = N-tile.
__global__ __launch_bounds__(256) void gemm_qkv(
    const bf16_t* __restrict__ Xq, const bf16_t* __restrict__ Xk, const bf16_t* __restrict__ Xv,
    const bf16_t* __restrict__ Wtq, const bf16_t* __restrict__ Wtk, const bf16_t* __restrict__ Wtv,
    const float* __restrict__ bq, const float* __restrict__ bk, const float* __restrict__ bv,
    bf16_t* __restrict__ Qd, bf16_t* __restrict__ Kd, bf16_t* __restrict__ Vt)
{
    __shared__ __align__(16) bf16_t As[4 * 128 * 32];   // 32 KB ring
    __shared__ __align__(16) bf16_t Bs[4 * 128 * 32];   // 32 KB ring
    int z = blockIdx.z;
    if (z == 0) {
        gemm_body<1>(Xq, Wtq, bq, QSCALE, Qd,
                     blockIdx.x * 128, blockIdx.y * 128, As, Bs);
    } else if (z == 1) {
        gemm_body<1>(Xk, Wtk, bk, 1.0f, Kd,
                     blockIdx.x * 128, blockIdx.y * 128, As, Bs);
    } else {
        // Vt = (Xv Wv)^T : A = Wtv (8 channel tiles = y), B = Xv (32 token tiles = x)
        gemm_body<2>(Wtv, Xv, bv, 1.0f, Vt,
                     blockIdx.y * 128, blockIdx.x * 128, As, Bs);
    }
}

// ---------------- output projection: 64x128 tile, 4-slot ring, depth-3 ------
__global__ __launch_bounds__(256) void gemm_out(
    const bf16_t* __restrict__ At, const bf16_t* __restrict__ Wto,
    const float* __restrict__ bo, float* __restrict__ out)
{
    const int K = 1024;
    __shared__ __align__(16) bf16_t As[4 * 64 * 32];    // 16 KB ring
    __shared__ __align__(16) bf16_t Bs[4 * 128 * 32];   // 32 KB ring

    int tid  = threadIdx.x;
    int wave = tid >> 6;
    int lane = tid & 63;
    int quad = lane >> 4;
    int ln   = lane & 15;

    int r0 = blockIdx.x * 64;
    int c0 = blockIdx.y * 128;

    f32x4 acc[4][2];
    for (int rb = 0; rb < 4; rb++)
        for (int cb = 0; cb < 2; cb++)
            acc[rb][cb] = (f32x4){0.f, 0.f, 0.f, 0.f};

    int sr = tid >> 2;
    int sk = (tid & 3) * 8;

    const bf16_t* gA0 = At  + (size_t)(r0 + sr) * K + sk;
    const bf16_t* gB0 = Wto + (size_t)(c0 + sr) * K + sk;
    const bf16_t* gB1 = gB0 + (size_t)64 * K;
    char* lA = (char*)As + wave * 1024;   // slot stride 4096 B
    char* lB = (char*)Bs + wave * 1024;   // slot stride 8192 B

    auto STAGE = [&](int s) {
        int k = s * 32;
        gload_lds16(gA0 + k, lA + (s & 3) * 4096);
        gload_lds16(gB0 + k, lB + (s & 3) * 8192);
        gload_lds16(gB1 + k, lB + (s & 3) * 8192 + 4096);
    };
    auto COMPUTE = [&](int t) {
        const bf16_t* Ab = As + (t & 3) * 2048;
        const bf16_t* Bb = Bs + (t & 3) * 4096;
        bf16x8 af[4], bfv[2];
        for (int rb = 0; rb < 4; rb++)
            af[rb] = *(const bf16x8*)&Ab[(rb * 16 + ln) * 32 + quad * 8];
        for (int cb = 0; cb < 2; cb++)
            bfv[cb] = *(const bf16x8*)&Bb[(wave * 32 + cb * 16 + ln) * 32 + quad * 8];
        for (int rb = 0; rb < 4; rb++)
            for (int cb = 0; cb < 2; cb++)
                acc[rb][cb] = __builtin_amdgcn_mfma_f32_16x16x32_bf16(af[rb], bfv[cb], acc[rb][cb], 0, 0, 0);
    };

    STAGE(0); STAGE(1); STAGE(2);

    for (int t = 0; t < 29; ++t) {
        WAITVM(6);
        __builtin_amdgcn_s_barrier();
        STAGE(t + 3);
        COMPUTE(t);
    }
    WAITVM(6); __builtin_amdgcn_s_barrier(); COMPUTE(29);
    WAITVM(3); __builtin_amdgcn_s_barrier(); COMPUTE(30);
    WAITVM(0); __builtin_amdgcn_s_barrier(); COMPUTE(31);

    for (int rb = 0; rb < 4; rb++) {
        for (int cb = 0; cb < 2; cb++) {
            int C = c0 + wave * 32 + cb * 16 + ln;
            float bn = bo[C];
            for (int r = 0; r < 4; r++) {
                int R = r0 + rb * 16 + quad * 4 + r;
                out[(size_t)R * DM + C] = acc[rb][cb][r] + bn;
            }
        }
    }
}

// ---------------- flash attention, LDS-staged, 32 q-rows per wave -----------
// Q,K: [bh][s][64] bf16 (Q pre-scaled by QSCALE -> exp2 domain).  Vt: [bh][d][s].
// grid (64, 8): x = bh (XCD locality), y = q-tile(128 rows, 32/wave).
__global__ __launch_bounds__(256) void attn6(
    const bf16_t* __restrict__ Q,
    const bf16_t* __restrict__ K,
    const bf16_t* __restrict__ Vt,
    bf16_t* __restrict__ O)
{
    __shared__ __align__(16) bf16_t Ks[64 * RS];
    __shared__ __align__(16) bf16_t Vs[64 * RS];
    __shared__ __align__(16) bf16_t Ps[4][32 * RS];

    int tid  = threadIdx.x;
    int wave = tid >> 6;
    int lane = tid & 63;
    int quad = lane >> 4;
    int ln   = lane & 15;

    int bh = blockIdx.x;
    int q0w = blockIdx.y * 128 + wave * 32;

    const bf16_t* Qb = Q  + (size_t)bh * 65536;
    const bf16_t* Kb = K  + (size_t)bh * 65536;
    const bf16_t* Vb = Vt + (size_t)bh * 65536;

    int srow = tid >> 3;
    int scol = (tid & 7) * 8;
    const bf16_t* gK0 = Kb + (size_t)srow * 64 + scol;
    const bf16_t* gK1 = gK0 + 32 * 64;
    const bf16_t* gV0 = Vb + (size_t)srow * 1024 + scol;
    const bf16_t* gV1 = gV0 + 32 * 1024;

    bf16x8 aq0[2], aq1[2];
    for (int h = 0; h < 2; h++) {
        aq0[h] = *(const bf16x8*)&Qb[(size_t)(q0w + h * 16 + ln) * 64 + quad * 8];
        aq1[h] = *(const bf16x8*)&Qb[(size_t)(q0w + h * 16 + ln) * 64 + 32 + quad * 8];
    }

    uint4 rK0 = *(const uint4*)gK0;
    uint4 rK1 = *(const uint4*)gK1;
    uint4 rV0 = *(const uint4*)gV0;
    uint4 rV1 = *(const uint4*)gV1;

    float l_lane[2] = {0.f, 0.f};
    f32x4 o_acc[2][4];
    for (int h = 0; h < 2; h++)
        for (int cb = 0; cb < 4; cb++)
            o_acc[h][cb] = (f32x4){0.f, 0.f, 0.f, 0.f};

    bf16_t* Pw = Ps[wave];

    for (int kt = 0; kt < 16; kt++) {
        __syncthreads();
        *(uint4*)&Ks[srow * RS + scol]        = rK0;
        *(uint4*)&Ks[(32 + srow) * RS + scol] = rK1;
        *(uint4*)&Vs[srow * RS + scol]        = rV0;
        *(uint4*)&Vs[(32 + srow) * RS + scol] = rV1;
        __syncthreads();

        if (kt < 15) {
            gK0 += 4096; gK1 += 4096; gV0 += 64; gV1 += 64;
            rK0 = *(const uint4*)gK0;
            rK1 = *(const uint4*)gK1;
            rV0 = *(const uint4*)gV0;
            rV1 = *(const uint4*)gV1;
        }

        // ---- S^T = K Q^T (two 16-row q-halves share K fragments) ----
        f32x4 sc[4][2];
        for (int kb = 0; kb < 4; kb++) {
            bf16x8 kf0 = *(const bf16x8*)&Ks[(kb * 16 + ln) * RS + quad * 8];
            bf16x8 kf1 = *(const bf16x8*)&Ks[(kb * 16 + ln) * RS + 32 + quad * 8];
            for (int h = 0; h < 2; h++) {
                f32x4 a = (f32x4){0.f, 0.f, 0.f, 0.f};
                a = __builtin_amdgcn_mfma_f32_16x16x32_bf16(kf0, aq0[h], a, 0, 0, 0);
                a = __builtin_amdgcn_mfma_f32_16x16x32_bf16(kf1, aq1[h], a, 0, 0, 0);
                sc[kb][h] = a;
            }
        }

        // ---- P = exp2(sc - PSHIFT) ----
        for (int kb = 0; kb < 4; kb++) {
            for (int h = 0; h < 2; h++) {
                float p0 = __builtin_amdgcn_exp2f(sc[kb][h][0] - PSHIFT);
                float p1 = __builtin_amdgcn_exp2f(sc[kb][h][1] - PSHIFT);
                float p2 = __builtin_amdgcn_exp2f(sc[kb][h][2] - PSHIFT);
                float p3 = __builtin_amdgcn_exp2f(sc[kb][h][3] - PSHIFT);
                l_lane[h] += (p0 + p1) + (p2 + p3);
                bf16x4 pk = (bf16x4){(bf16_t)p0, (bf16_t)p1, (bf16_t)p2, (bf16_t)p3};
                *(bf16x4*)&Pw[(h * 16 + ln) * RS + kb * 16 + quad * 4] = pk;
            }
        }

        // ---- O += P V (V fragments shared across q-halves) ----
        for (int kc = 0; kc < 2; kc++) {
            bf16x8 ap0 = *(const bf16x8*)&Pw[ln * RS + kc * 32 + quad * 8];
            bf16x8 ap1 = *(const bf16x8*)&Pw[(16 + ln) * RS + kc * 32 + quad * 8];
            for (int cb = 0; cb < 4; cb++) {
                bf16x8 vf = *(const bf16x8*)&Vs[(cb * 16 + ln) * RS + kc * 32 + quad * 8];
                o_acc[0][cb] = __builtin_amdgcn_mfma_f32_16x16x32_bf16(ap0, vf, o_acc[0][cb], 0, 0, 0);
                o_acc[1][cb] = __builtin_amdgcn_mfma_f32_16x16x32_bf16(ap1, vf, o_acc[1][cb], 0, 0, 0);
            }
        }
    }

    int b = bh >> 4, hd = bh & 15;
    for (int h = 0; h < 2; h++) {
        float l = l_lane[h];
        l += __shfl_xor(l, 16);
        l += __shfl_xor(l, 32);
        float invq[4];
        for (int r = 0; r < 4; r++)
            invq[r] = 1.f / __shfl(l, quad * 4 + r);
        for (int cb = 0; cb < 4; cb++) {
            for (int r = 0; r < 4; r++) {
                int q = q0w + h * 16 + quad * 4 + r;
                int d = cb * 16 + ln;
                O[((size_t)b * 1024 + q) * DM + hd * 64 + d] = (bf16_t)(o_acc[h][cb][r] * invq[r]);
            }
        }
    }
}

extern "C" void kernel_launch(void* const* d_in, const int* in_sizes, int n_in,
                              void* d_out, int out_size, void* d_ws, size_t ws_size,
                              hipStream_t stream) {
    const float* q_in = (const float*)d_in[0];
    const float* k_in = (const float*)d_in[1];
    const float* v_in = (const float*)d_in[2];
    const float* Wq   = (const float*)d_in[3];
    const float* bq   = (const float*)d_in[4];
    const float* Wk   = (const float*)d_in[5];
    const float* bk   = (const float*)d_in[6];
    const float* Wv   = (const float*)d_in[7];
    const float* bv   = (const float*)d_in[8];
    const float* Wo   = (const float*)d_in[9];
    const float* bo   = (const float*)d_in[10];

    char* ws = (char*)d_ws;
    const size_t MB = 1024ull * 1024ull;
    bf16_t* Xq  = (bf16_t*)(ws);             // 8 MB
    bf16_t* Xk  = (bf16_t*)(ws + 8 * MB);
    bf16_t* Xv  = (bf16_t*)(ws + 16 * MB);
    bf16_t* Wtq = (bf16_t*)(ws + 24 * MB);
    bf16_t* Wtk = (bf16_t*)(ws + 26 * MB);
    bf16_t* Wtv = (bf16_t*)(ws + 28 * MB);
    bf16_t* Wto = (bf16_t*)(ws + 30 * MB);
    bf16_t* Qd  = (bf16_t*)(ws + 32 * MB);   // [bh][s][d]
    bf16_t* Kd  = (bf16_t*)(ws + 40 * MB);   // [bh][s][d]
    bf16_t* Vt  = (bf16_t*)(ws + 48 * MB);   // [bh][d][s]
    bf16_t* At  = Xq;                        // attn out aliases Xq (dead by then)

    prep<<<7168, 256, 0, stream>>>(q_in, k_in, v_in, Xq, Xk, Xv,
                                   Wq, Wk, Wv, Wo, Wtq, Wtk, Wtv, Wto);

    gemm_qkv<<<dim3(32, 8, 3), 256, 0, stream>>>(Xq, Xk, Xv,
                                                 Wtq, Wtk, Wtv, bq, bk, bv, Qd, Kd, Vt);

    attn6<<<dim3(64, 8), 256, 0, stream>>>(Qd, Kd, Vt, At);

    gemm_out<<<dim3(64, 8), 256, 0, stream>>>(At, Wto, bo, (float*)d_out);
}

// Round 4
// 214.117 us; speedup vs baseline: 1.0121x; 1.0121x over previous
//
#include <hip/hip_runtime.h>
#include <hip/hip_bf16.h>
#include <cstdint>
#include <cstddef>

typedef __bf16 bf16_t;
typedef __bf16 bf16x8 __attribute__((ext_vector_type(8)));
typedef __bf16 bf16x4 __attribute__((ext_vector_type(4)));
typedef float f32x4 __attribute__((ext_vector_type(4)));

#define DM 1024
#define NHEAD 16
#define DHEAD 64

// Q scale folded into projection: 1/sqrt(64) * log2(e)
#define QSCALE 0.18033688011112042f
// fixed exp2 shift (cancels exactly in O/l)
#define PSHIFT 4.0f
// padded LDS row stride for attention tiles
#define RS 72

// counted vmcnt: lets N loads stay in flight across a raw barrier (T4)
#define WAITVM(N) asm volatile("s_waitcnt vmcnt(" #N ")" ::: "memory")
#define BARRIER() do { __builtin_amdgcn_s_barrier(); asm volatile("" ::: "memory"); } while (0)

__device__ __forceinline__ void gload_lds16(const void* g, void* l) {
    __builtin_amdgcn_global_load_lds(
        (const __attribute__((address_space(1))) void*)g,
        (__attribute__((address_space(3))) void*)l,
        16, 0, 0);
}

__device__ __forceinline__ uint4 cvt8(float4 lo, float4 hi) {
    union { bf16_t b[8]; uint4 u; } o;
    o.b[0] = (bf16_t)lo.x; o.b[1] = (bf16_t)lo.y; o.b[2] = (bf16_t)lo.z; o.b[3] = (bf16_t)lo.w;
    o.b[4] = (bf16_t)hi.x; o.b[5] = (bf16_t)hi.y; o.b[6] = (bf16_t)hi.z; o.b[7] = (bf16_t)hi.w;
    return o.u;
}

// ---------------- prep: fused cast(3 tensors) + transpose(4 weights) ---------
__global__ void prep(
    const float* __restrict__ q_in, const float* __restrict__ k_in, const float* __restrict__ v_in,
    bf16_t* __restrict__ Xq, bf16_t* __restrict__ Xk, bf16_t* __restrict__ Xv,
    const float* __restrict__ w0, const float* __restrict__ w1,
    const float* __restrict__ w2, const float* __restrict__ w3,
    bf16_t* __restrict__ t0, bf16_t* __restrict__ t1,
    bf16_t* __restrict__ t2, bf16_t* __restrict__ t3)
{
    __shared__ float tile[64][65];
    int id = blockIdx.x;
    if (id < 6144) {
        int plane = id >> 11;
        int blk = id & 2047;
        const float* x = plane == 0 ? q_in : plane == 1 ? k_in : v_in;
        bf16_t* y      = plane == 0 ? Xq   : plane == 1 ? Xk   : Xv;
        int i = (blk * 256 + threadIdx.x) * 8;
        float4 lo = *(const float4*)&x[i];
        float4 hi = *(const float4*)&x[i + 4];
        *(uint4*)&y[i] = cvt8(lo, hi);
    } else {
        int t = id - 6144;
        int zi = t >> 8;
        int blk = t & 255;
        const float* w = zi == 0 ? w0 : zi == 1 ? w1 : zi == 2 ? w2 : w3;
        bf16_t* wt     = zi == 0 ? t0 : zi == 1 ? t1 : zi == 2 ? t2 : t3;
        int bx = (blk & 15) * 64;    // n base
        int by = (blk >> 4) * 64;    // k base
        int tx = threadIdx.x & 63, ty = threadIdx.x >> 6;   // 64 x 4
        for (int j = 0; j < 64; j += 4)
            tile[ty + j][tx] = w[(size_t)(by + ty + j) * DM + bx + tx];
        __syncthreads();
        int nl = threadIdx.x >> 3;           // 0..31
        int kl = (threadIdx.x & 7) * 8;      // 0..56
        for (int j = 0; j < 64; j += 32) {
            int n = nl + j;
            union { bf16_t b[8]; uint4 u; } o;
            for (int i = 0; i < 8; i++)
                o.b[i] = (bf16_t)tile[kl + i][n];
            *(uint4*)&wt[(size_t)(bx + n) * DM + by + kl] = o.u;
        }
    }
}

// ------ GEMM core: 256x256 tile, BK=32, triple-buffer, counted-vmcnt --------
// 512 thr = 8 waves (2 M x 4 N), per-wave out 128x64, acc[8][4] f32x4.
// LDS: 3 buffers x (A 16KB + B 16KB) = 96KB -> 1 block/CU (grid 192 <= 256CU).
// Ledger (per thread, 4 loads/K-tile, FIFO vmcnt): stage t+2 into buf (t+2)%3
// during K-tile t (buffer free since t-1 ended -> no live overwrite). Boundary
// wait vmcnt(4) retires t+1's 4 loads, keeps t+2's 4 in flight (never 0).
// Barrier publishes cross-wave LDS staging. T5 setprio around MFMA clusters.
// MODE 1: bf16 out [bh][s][d], v=(acc+bias[C])*scale
// MODE 2: bf16 out Vt [bh][d][s], R=channel, C=token, v=acc+bias[R]
template <int MODE>
__device__ __forceinline__ void gemm_body256(
    const bf16_t* __restrict__ A, const bf16_t* __restrict__ Bt,
    const float* __restrict__ bias, float scale,
    bf16_t* __restrict__ Cb,
    int r0, int c0, bf16_t* AsP, bf16_t* BsP)
{
    const int K = 1024;
    int tid  = threadIdx.x;
    int wave = tid >> 6;
    int lane = tid & 63;
    int quad = lane >> 4;
    int ln   = lane & 15;
    int wm   = wave >> 2;    // 0..1 : row half (rows wm*128..+128)
    int wn   = wave & 3;     // 0..3 : col quarter (cols wn*64..+64)

    f32x4 acc[8][4];
    for (int m = 0; m < 8; m++)
        for (int n = 0; n < 4; n++)
            acc[m][n] = (f32x4){0.f, 0.f, 0.f, 0.f};

    int srow = tid >> 2;          // 0..127
    int sk   = (tid & 3) * 8;     // 0,8,16,24 (bf16 elems)

    const bf16_t* gA = &A[(size_t)(r0 + srow) * K + sk];
    const bf16_t* gB = &Bt[(size_t)(c0 + srow) * K + sk];
    char* lA = (char*)AsP + tid * 16;   // linear pass layout: row=tid>>2, 16B chunk=tid&3
    char* lB = (char*)BsP + tid * 16;

    auto STAGE_A = [&](int s, int b) {
        int k = s * 32;
        gload_lds16(gA + k, lA + b * 16384);                       // rows 0..127
        gload_lds16(gA + (size_t)128 * K + k, lA + b * 16384 + 8192); // rows 128..255
    };
    auto STAGE_B = [&](int s, int b) {
        int k = s * 32;
        gload_lds16(gB + k, lB + b * 16384);
        gload_lds16(gB + (size_t)128 * K + k, lB + b * 16384 + 8192);
    };

    // prologue: K-tiles 0 and 1 staged; retire t0, keep t1 in flight
    STAGE_A(0, 0); STAGE_B(0, 0);
    STAGE_A(1, 1); STAGE_B(1, 1);
    WAITVM(4);
    BARRIER();

    int b = 0, b2 = 2;
    for (int t = 0; t < 32; ++t) {
        const bf16_t* Ab = AsP + b * 8192;   // 8192 elems = 16KB buffer
        const bf16_t* Bb = BsP + b * 8192;

        if (t < 30) STAGE_A(t + 2, b2);

        bf16x8 bfr[4];
        #pragma unroll
        for (int nf = 0; nf < 4; nf++)
            bfr[nf] = *(const bf16x8*)&Bb[(wn * 64 + nf * 16 + ln) * 32 + quad * 8];

        bf16x8 af[4];
        #pragma unroll
        for (int mf = 0; mf < 4; mf++)
            af[mf] = *(const bf16x8*)&Ab[(wm * 128 + mf * 16 + ln) * 32 + quad * 8];
        __builtin_amdgcn_s_setprio(1);
        #pragma unroll
        for (int mf = 0; mf < 4; mf++)
            #pragma unroll
            for (int nf = 0; nf < 4; nf++)
                acc[mf][nf] = __builtin_amdgcn_mfma_f32_16x16x32_bf16(af[mf], bfr[nf], acc[mf][nf], 0, 0, 0);
        __builtin_amdgcn_s_setprio(0);

        if (t < 30) STAGE_B(t + 2, b2);

        #pragma unroll
        for (int mf = 0; mf < 4; mf++)
            af[mf] = *(const bf16x8*)&Ab[(wm * 128 + 64 + mf * 16 + ln) * 32 + quad * 8];
        __builtin_amdgcn_s_setprio(1);
        #pragma unroll
        for (int mf = 0; mf < 4; mf++)
            #pragma unroll
            for (int nf = 0; nf < 4; nf++)
                acc[4 + mf][nf] = __builtin_amdgcn_mfma_f32_16x16x32_bf16(af[mf], bfr[nf], acc[4 + mf][nf], 0, 0, 0);
        __builtin_amdgcn_s_setprio(0);

        if (t < 30)      { WAITVM(4); }   // retire t+1's 4; t+2's 4 stay in flight
        else if (t == 30){ WAITVM(0); }   // retire t31 (issued at t29)
        if (t < 31) BARRIER();

        b  = (b  == 2) ? 0 : b  + 1;
        b2 = (b2 == 2) ? 0 : b2 + 1;
    }

    for (int m = 0; m < 8; m++) {
        for (int nf = 0; nf < 4; nf++) {
            int C = c0 + wn * 64 + nf * 16 + ln;
            for (int r = 0; r < 4; r++) {
                int R = r0 + wm * 128 + m * 16 + quad * 4 + r;
                float v = acc[m][nf][r];
                if (MODE == 1) {
                    int bb = R >> 10, s = R & 1023;
                    int h = C >> 6,  d = C & 63;
                    Cb[(((size_t)bb * NHEAD + h) * 1024 + s) * DHEAD + d] =
                        (bf16_t)((v + bias[C]) * scale);
                } else {
                    Cb[((size_t)(C >> 10) * 1024 + R) * 1024 + (C & 1023)] =
                        (bf16_t)(v + bias[R]);
                }
            }
        }
    }
}

// grid (64, 1, 3): 192 blocks, 512 threads. xs = bijective XCD swizzle (64%8==0).
__global__ __launch_bounds__(512, 2) void gemm_qkv(
    const bf16_t* __restrict__ Xq, const bf16_t* __restrict__ Xk, const bf16_t* __restrict__ Xv,
    const bf16_t* __restrict__ Wtq, const bf16_t* __restrict__ Wtk, const bf16_t* __restrict__ Wtv,
    const float* __restrict__ bq, const float* __restrict__ bk, const float* __restrict__ bv,
    bf16_t* __restrict__ Qd, bf16_t* __restrict__ Kd, bf16_t* __restrict__ Vt)
{
    __shared__ __align__(16) bf16_t As[3 * 256 * 32];   // 48 KB
    __shared__ __align__(16) bf16_t Bs[3 * 256 * 32];   // 48 KB
    int x  = blockIdx.x;
    int xs = (x & 7) * 8 + (x >> 3);
    int z  = blockIdx.z;
    if (z == 0) {
        gemm_body256<1>(Xq, Wtq, bq, QSCALE, Qd,
                        (xs >> 2) * 256, (xs & 3) * 256, As, Bs);
    } else if (z == 1) {
        gemm_body256<1>(Xk, Wtk, bk, 1.0f, Kd,
                        (xs >> 2) * 256, (xs & 3) * 256, As, Bs);
    } else {
        // Vt = (Xv Wv)^T : A = Wtv (M=1024 -> 4 tiles), B = Xv (N=4096 -> 16 tiles)
        gemm_body256<2>(Wtv, Xv, bv, 1.0f, Vt,
                        (xs & 3) * 256, (xs >> 2) * 256, As, Bs);
    }
}

// ---------------- output projection: 64x128 tile, 2-phase dbuf (round-2) ----
__global__ __launch_bounds__(256) void gemm_out(
    const bf16_t* __restrict__ At, const bf16_t* __restrict__ Wto,
    const float* __restrict__ bo, float* __restrict__ out)
{
    const int K = 1024;
    __shared__ __align__(16) bf16_t As[2 * 64 * 32];    // 4 KB / buffer
    __shared__ __align__(16) bf16_t Bs[2 * 128 * 32];   // 8 KB / buffer

    int tid  = threadIdx.x;
    int wave = tid >> 6;
    int lane = tid & 63;
    int quad = lane >> 4;
    int ln   = lane & 15;

    int r0 = blockIdx.x * 64;
    int c0 = blockIdx.y * 128;

    f32x4 acc[4][2];
    for (int rb = 0; rb < 4; rb++)
        for (int cb = 0; cb < 2; cb++)
            acc[rb][cb] = (f32x4){0.f, 0.f, 0.f, 0.f};

    int sr = tid >> 2;
    int sk = (tid & 3) * 8;

    const bf16_t* gA0 = At  + (size_t)(r0 + sr) * K + sk;
    const bf16_t* gB0 = Wto + (size_t)(c0 + sr) * K + sk;
    const bf16_t* gB1 = gB0 + (size_t)64 * K;
    char* lA = (char*)As + wave * 1024;   // buffer stride 4096 B
    char* lB = (char*)Bs + wave * 1024;   // buffer stride 8192 B

    gload_lds16(gA0, lA);
    gload_lds16(gB0, lB);
    gload_lds16(gB1, lB + 4096);
    __syncthreads();

    int cur = 0;
    for (int k0 = 0; k0 < K; k0 += 32) {
        int nxt = cur ^ 1;
        if (k0 + 32 < K) {
            gload_lds16(gA0 + k0 + 32, lA + nxt * 4096);
            gload_lds16(gB0 + k0 + 32, lB + nxt * 8192);
            gload_lds16(gB1 + k0 + 32, lB + nxt * 8192 + 4096);
        }
        const bf16_t* Ab = As + cur * 2048;
        const bf16_t* Bb = Bs + cur * 4096;

        bf16x8 af[4], bfv[2];
        for (int rb = 0; rb < 4; rb++)
            af[rb] = *(const bf16x8*)&Ab[(rb * 16 + ln) * 32 + quad * 8];
        for (int cb = 0; cb < 2; cb++)
            bfv[cb] = *(const bf16x8*)&Bb[(wave * 32 + cb * 16 + ln) * 32 + quad * 8];
        for (int rb = 0; rb < 4; rb++)
            for (int cb = 0; cb < 2; cb++)
                acc[rb][cb] = __builtin_amdgcn_mfma_f32_16x16x32_bf16(af[rb], bfv[cb], acc[rb][cb], 0, 0, 0);

        __syncthreads();
        cur = nxt;
    }

    for (int rb = 0; rb < 4; rb++) {
        for (int cb = 0; cb < 2; cb++) {
            int C = c0 + wave * 32 + cb * 16 + ln;
            float bn = bo[C];
            for (int r = 0; r < 4; r++) {
                int R = r0 + rb * 16 + quad * 4 + r;
                out[(size_t)R * DM + C] = acc[rb][cb][r] + bn;
            }
        }
    }
}

// ---------------- flash attention, LDS-staged, 32 q-rows per wave -----------
__global__ __launch_bounds__(256) void attn6(
    const bf16_t* __restrict__ Q,
    const bf16_t* __restrict__ K,
    const bf16_t* __restrict__ Vt,
    bf16_t* __restrict__ O)
{
    __shared__ __align__(16) bf16_t Ks[64 * RS];
    __shared__ __align__(16) bf16_t Vs[64 * RS];
    __shared__ __align__(16) bf16_t Ps[4][32 * RS];

    int tid  = threadIdx.x;
    int wave = tid >> 6;
    int lane = tid & 63;
    int quad = lane >> 4;
    int ln   = lane & 15;

    int bh = blockIdx.x;
    int q0w = blockIdx.y * 128 + wave * 32;

    const bf16_t* Qb = Q  + (size_t)bh * 65536;
    const bf16_t* Kb = K  + (size_t)bh * 65536;
    const bf16_t* Vb = Vt + (size_t)bh * 65536;

    int srow = tid >> 3;
    int scol = (tid & 7) * 8;
    const bf16_t* gK0 = Kb + (size_t)srow * 64 + scol;
    const bf16_t* gK1 = gK0 + 32 * 64;
    const bf16_t* gV0 = Vb + (size_t)srow * 1024 + scol;
    const bf16_t* gV1 = gV0 + 32 * 1024;

    bf16x8 aq0[2], aq1[2];
    for (int h = 0; h < 2; h++) {
        aq0[h] = *(const bf16x8*)&Qb[(size_t)(q0w + h * 16 + ln) * 64 + quad * 8];
        aq1[h] = *(const bf16x8*)&Qb[(size_t)(q0w + h * 16 + ln) * 64 + 32 + quad * 8];
    }

    uint4 rK0 = *(const uint4*)gK0;
    uint4 rK1 = *(const uint4*)gK1;
    uint4 rV0 = *(const uint4*)gV0;
    uint4 rV1 = *(const uint4*)gV1;

    float l_lane[2] = {0.f, 0.f};
    f32x4 o_acc[2][4];
    for (int h = 0; h < 2; h++)
        for (int cb = 0; cb < 4; cb++)
            o_acc[h][cb] = (f32x4){0.f, 0.f, 0.f, 0.f};

    bf16_t* Pw = Ps[wave];

    for (int kt = 0; kt < 16; kt++) {
        __syncthreads();
        *(uint4*)&Ks[srow * RS + scol]        = rK0;
        *(uint4*)&Ks[(32 + srow) * RS + scol] = rK1;
        *(uint4*)&Vs[srow * RS + scol]        = rV0;
        *(uint4*)&Vs[(32 + srow) * RS + scol] = rV1;
        __syncthreads();

        if (kt < 15) {
            gK0 += 4096; gK1 += 4096; gV0 += 64; gV1 += 64;
            rK0 = *(const uint4*)gK0;
            rK1 = *(const uint4*)gK1;
            rV0 = *(const uint4*)gV0;
            rV1 = *(const uint4*)gV1;
        }

        // ---- S^T = K Q^T (two 16-row q-halves share K fragments) ----
        f32x4 sc[4][2];
        for (int kb = 0; kb < 4; kb++) {
            bf16x8 kf0 = *(const bf16x8*)&Ks[(kb * 16 + ln) * RS + quad * 8];
            bf16x8 kf1 = *(const bf16x8*)&Ks[(kb * 16 + ln) * RS + 32 + quad * 8];
            for (int h = 0; h < 2; h++) {
                f32x4 a = (f32x4){0.f, 0.f, 0.f, 0.f};
                a = __builtin_amdgcn_mfma_f32_16x16x32_bf16(kf0, aq0[h], a, 0, 0, 0);
                a = __builtin_amdgcn_mfma_f32_16x16x32_bf16(kf1, aq1[h], a, 0, 0, 0);
                sc[kb][h] = a;
            }
        }

        // ---- P = exp2(sc - PSHIFT) ----
        for (int kb = 0; kb < 4; kb++) {
            for (int h = 0; h < 2; h++) {
                float p0 = __builtin_amdgcn_exp2f(sc[kb][h][0] - PSHIFT);
                float p1 = __builtin_amdgcn_exp2f(sc[kb][h][1] - PSHIFT);
                float p2 = __builtin_amdgcn_exp2f(sc[kb][h][2] - PSHIFT);
                float p3 = __builtin_amdgcn_exp2f(sc[kb][h][3] - PSHIFT);
                l_lane[h] += (p0 + p1) + (p2 + p3);
                bf16x4 pk = (bf16x4){(bf16_t)p0, (bf16_t)p1, (bf16_t)p2, (bf16_t)p3};
                *(bf16x4*)&Pw[(h * 16 + ln) * RS + kb * 16 + quad * 4] = pk;
            }
        }

        // ---- O += P V (V fragments shared across q-halves) ----
        for (int kc = 0; kc < 2; kc++) {
            bf16x8 ap0 = *(const bf16x8*)&Pw[ln * RS + kc * 32 + quad * 8];
            bf16x8 ap1 = *(const bf16x8*)&Pw[(16 + ln) * RS + kc * 32 + quad * 8];
            for (int cb = 0; cb < 4; cb++) {
                bf16x8 vf = *(const bf16x8*)&Vs[(cb * 16 + ln) * RS + kc * 32 + quad * 8];
                o_acc[0][cb] = __builtin_amdgcn_mfma_f32_16x16x32_bf16(ap0, vf, o_acc[0][cb], 0, 0, 0);
                o_acc[1][cb] = __builtin_amdgcn_mfma_f32_16x16x32_bf16(ap1, vf, o_acc[1][cb], 0, 0, 0);
            }
        }
    }

    int b = bh >> 4, hd = bh & 15;
    for (int h = 0; h < 2; h++) {
        float l = l_lane[h];
        l += __shfl_xor(l, 16);
        l += __shfl_xor(l, 32);
        float invq[4];
        for (int r = 0; r < 4; r++)
            invq[r] = 1.f / __shfl(l, quad * 4 + r);
        for (int cb = 0; cb < 4; cb++) {
            for (int r = 0; r < 4; r++) {
                int q = q0w + h * 16 + quad * 4 + r;
                int d = cb * 16 + ln;
                O[((size_t)b * 1024 + q) * DM + hd * 64 + d] = (bf16_t)(o_acc[h][cb][r] * invq[r]);
            }
        }
    }
}

extern "C" void kernel_launch(void* const* d_in, const int* in_sizes, int n_in,
                              void* d_out, int out_size, void* d_ws, size_t ws_size,
                              hipStream_t stream) {
    const float* q_in = (const float*)d_in[0];
    const float* k_in = (const float*)d_in[1];
    const float* v_in = (const float*)d_in[2];
    const float* Wq   = (const float*)d_in[3];
    const float* bq   = (const float*)d_in[4];
    const float* Wk   = (const float*)d_in[5];
    const float* bk   = (const float*)d_in[6];
    const float* Wv   = (const float*)d_in[7];
    const float* bv   = (const float*)d_in[8];
    const float* Wo   = (const float*)d_in[9];
    const float* bo   = (const float*)d_in[10];

    char* ws = (char*)d_ws;
    const size_t MB = 1024ull * 1024ull;
    bf16_t* Xq  = (bf16_t*)(ws);             // 8 MB
    bf16_t* Xk  = (bf16_t*)(ws + 8 * MB);
    bf16_t* Xv  = (bf16_t*)(ws + 16 * MB);
    bf16_t* Wtq = (bf16_t*)(ws + 24 * MB);
    bf16_t* Wtk = (bf16_t*)(ws + 26 * MB);
    bf16_t* Wtv = (bf16_t*)(ws + 28 * MB);
    bf16_t* Wto = (bf16_t*)(ws + 30 * MB);
    bf16_t* Qd  = (bf16_t*)(ws + 32 * MB);   // [bh][s][d]
    bf16_t* Kd  = (bf16_t*)(ws + 40 * MB);   // [bh][s][d]
    bf16_t* Vt  = (bf16_t*)(ws + 48 * MB);   // [bh][d][s]
    bf16_t* At  = Xq;                        // attn out aliases Xq (dead by then)

    prep<<<7168, 256, 0, stream>>>(q_in, k_in, v_in, Xq, Xk, Xv,
                                   Wq, Wk, Wv, Wo, Wtq, Wtk, Wtv, Wto);

    gemm_qkv<<<dim3(64, 1, 3), 512, 0, stream>>>(Xq, Xk, Xv,
                                                 Wtq, Wtk, Wtv, bq, bk, bv, Qd, Kd, Vt);

    attn6<<<dim3(64, 8), 256, 0, stream>>>(Qd, Kd, Vt, At);

    gemm_out<<<dim3(64, 8), 256, 0, stream>>>(At, Wto, bo, (float*)d_out);
}

// Round 5
// 202.813 us; speedup vs baseline: 1.0685x; 1.0557x over previous
//
#include <hip/hip_runtime.h>
#include <hip/hip_bf16.h>
#include <cstdint>
#include <cstddef>

typedef __bf16 bf16_t;
typedef __bf16 bf16x8 __attribute__((ext_vector_type(8)));
typedef __bf16 bf16x4 __attribute__((ext_vector_type(4)));
typedef float f32x4 __attribute__((ext_vector_type(4)));

#define DM 1024
#define NHEAD 16
#define DHEAD 64

// Q scale folded into projection: 1/sqrt(64) * log2(e)
#define QSCALE 0.18033688011112042f
// fixed exp2 shift (cancels exactly in O/l)
#define PSHIFT 4.0f
// padded LDS row stride for attention tiles
#define RS 72

// counted vmcnt: lets N loads stay in flight across a raw barrier (T4)
#define WAITVM(N) asm volatile("s_waitcnt vmcnt(" #N ")" ::: "memory")
#define LGKM0()   asm volatile("s_waitcnt lgkmcnt(0)" ::: "memory")
#define BAR()     do { asm volatile("" ::: "memory"); __builtin_amdgcn_s_barrier(); \
                       asm volatile("" ::: "memory"); } while (0)

__device__ __forceinline__ void gload_lds16(const void* g, void* l) {
    __builtin_amdgcn_global_load_lds(
        (const __attribute__((address_space(1))) void*)g,
        (__attribute__((address_space(3))) void*)l,
        16, 0, 0);
}

__device__ __forceinline__ uint4 cvt8(float4 lo, float4 hi) {
    union { bf16_t b[8]; uint4 u; } o;
    o.b[0] = (bf16_t)lo.x; o.b[1] = (bf16_t)lo.y; o.b[2] = (bf16_t)lo.z; o.b[3] = (bf16_t)lo.w;
    o.b[4] = (bf16_t)hi.x; o.b[5] = (bf16_t)hi.y; o.b[6] = (bf16_t)hi.z; o.b[7] = (bf16_t)hi.w;
    return o.u;
}

// ---------------- prep: fused cast(3 tensors) + transpose(4 weights) ---------
__global__ void prep(
    const float* __restrict__ q_in, const float* __restrict__ k_in, const float* __restrict__ v_in,
    bf16_t* __restrict__ Xq, bf16_t* __restrict__ Xk, bf16_t* __restrict__ Xv,
    const float* __restrict__ w0, const float* __restrict__ w1,
    const float* __restrict__ w2, const float* __restrict__ w3,
    bf16_t* __restrict__ t0, bf16_t* __restrict__ t1,
    bf16_t* __restrict__ t2, bf16_t* __restrict__ t3)
{
    __shared__ float tile[64][65];
    int id = blockIdx.x;
    if (id < 6144) {
        int plane = id >> 11;
        int blk = id & 2047;
        const float* x = plane == 0 ? q_in : plane == 1 ? k_in : v_in;
        bf16_t* y      = plane == 0 ? Xq   : plane == 1 ? Xk   : Xv;
        int i = (blk * 256 + threadIdx.x) * 8;
        float4 lo = *(const float4*)&x[i];
        float4 hi = *(const float4*)&x[i + 4];
        *(uint4*)&y[i] = cvt8(lo, hi);
    } else {
        int t = id - 6144;
        int zi = t >> 8;
        int blk = t & 255;
        const float* w = zi == 0 ? w0 : zi == 1 ? w1 : zi == 2 ? w2 : w3;
        bf16_t* wt     = zi == 0 ? t0 : zi == 1 ? t1 : zi == 2 ? t2 : t3;
        int bx = (blk & 15) * 64;    // n base
        int by = (blk >> 4) * 64;    // k base
        int tx = threadIdx.x & 63, ty = threadIdx.x >> 6;   // 64 x 4
        for (int j = 0; j < 64; j += 4)
            tile[ty + j][tx] = w[(size_t)(by + ty + j) * DM + bx + tx];
        __syncthreads();
        int nl = threadIdx.x >> 3;           // 0..31
        int kl = (threadIdx.x & 7) * 8;      // 0..56
        for (int j = 0; j < 64; j += 32) {
            int n = nl + j;
            union { bf16_t b[8]; uint4 u; } o;
            for (int i = 0; i < 8; i++)
                o.b[i] = (bf16_t)tile[kl + i][n];
            *(uint4*)&wt[(size_t)(bx + n) * DM + by + kl] = o.u;
        }
    }
}

// ---- GEMM core: 128x128 tile, BK=32, 3-buffer depth-2 counted vmcnt --------
// Ledger (4 loads/stage, per-wave FIFO vmcnt): prologue stages t0,t1; vmcnt(4)
// retires t0. During step t: stage t+2 into slot (t+2)%3 (its readers, step
// t-1, finished at the previous barrier). End of step: vmcnt(4) retires t+1's
// loads, leaves t+2's 4 in flight ACROSS the raw s_barrier (no full drain ->
// load latency spans 2 compute steps). Unroll-by-3 makes slot indices
// compile-time (round-3's ring-VALU bloat avoided). LDS 48KB -> 3 blocks/CU,
// matching grid 768/256 (round-3's occupancy collapse avoided).
// Chunk-XOR swizzle (both sides, rule 21): LDS[r][c] holds G[r][c^((r>>1)&3)]
// -> 16-lane ds_read_b128 spreads over 8 slots = 2-way banks (free).
// MODE 1: bf16 out [bh][s][d], v=(acc+bias[C])*scale
// MODE 2: bf16 out Vt [bh][d][s], R=channel, C=token, v=acc+bias[R]
template <int MODE>
__device__ __forceinline__ void gemm_body(
    const bf16_t* __restrict__ A, const bf16_t* __restrict__ Bt,
    const float* __restrict__ bias, float scale,
    bf16_t* __restrict__ Cb,
    int r0, int c0, bf16_t* AsP, bf16_t* BsP)
{
    const int K = 1024;
    int tid  = threadIdx.x;
    int wave = tid >> 6;
    int lane = tid & 63;
    int quad = lane >> 4;
    int ln   = lane & 15;
    int wr   = wave >> 1;
    int wc   = wave & 1;

    f32x4 acc[4][4];
    for (int rb = 0; rb < 4; rb++)
        for (int cb = 0; cb < 4; cb++)
            acc[rb][cb] = (f32x4){0.f, 0.f, 0.f, 0.f};

    int sr = tid >> 2;
    // swizzled source chunk: c_src = c_dest ^ ((r>>1)&3)
    int sk = (((tid & 3) ^ ((tid >> 3) & 3))) * 8;

    const bf16_t* gA0 = &A[(size_t)(r0 + sr) * K + sk];
    const bf16_t* gA1 = gA0 + (size_t)64 * K;
    const bf16_t* gB0 = &Bt[(size_t)(c0 + sr) * K + sk];
    const bf16_t* gB1 = gB0 + (size_t)64 * K;
    char* lA = (char*)AsP + wave * 1024;   // slot stride 8192 B
    char* lB = (char*)BsP + wave * 1024;

    int ch = (quad ^ ((ln >> 1) & 3)) * 8;   // swizzled read chunk (elems)

    auto STAGE = [&](int s, int slot) {
        int k = s * 32;
        int off = slot * 8192;
        gload_lds16(gA0 + k, lA + off);
        gload_lds16(gA1 + k, lA + off + 4096);
        gload_lds16(gB0 + k, lB + off);
        gload_lds16(gB1 + k, lB + off + 4096);
    };
    auto COMPUTE = [&](int slot) {
        const bf16_t* Ab = AsP + slot * 4096;   // 4096 elems = 8 KB slot
        const bf16_t* Bb = BsP + slot * 4096;
        bf16x8 af[4], bfv[4];
        #pragma unroll
        for (int rb = 0; rb < 4; rb++)
            af[rb] = *(const bf16x8*)&Ab[(wr * 64 + rb * 16 + ln) * 32 + ch];
        #pragma unroll
        for (int cb = 0; cb < 4; cb++)
            bfv[cb] = *(const bf16x8*)&Bb[(wc * 64 + cb * 16 + ln) * 32 + ch];
        __builtin_amdgcn_s_setprio(1);
        #pragma unroll
        for (int rb = 0; rb < 4; rb++)
            #pragma unroll
            for (int cb = 0; cb < 4; cb++)
                acc[rb][cb] = __builtin_amdgcn_mfma_f32_16x16x32_bf16(af[rb], bfv[cb], acc[rb][cb], 0, 0, 0);
        __builtin_amdgcn_s_setprio(0);
    };

    STAGE(0, 0); STAGE(1, 1);
    WAITVM(4);           // retire t0's 4; t1's stay in flight
    BAR();

    for (int tt = 0; tt < 30; tt += 3) {
        STAGE(tt + 2, 2); COMPUTE(0); WAITVM(4); BAR();
        STAGE(tt + 3, 0); COMPUTE(1); WAITVM(4); BAR();
        STAGE(tt + 4, 1); COMPUTE(2); WAITVM(4); BAR();
    }
    COMPUTE(0); WAITVM(0); BAR();   // t=30; retire t31's loads
    COMPUTE(1);                      // t=31

    for (int rb = 0; rb < 4; rb++) {
        for (int cb = 0; cb < 4; cb++) {
            int C = c0 + wc * 64 + cb * 16 + ln;
            for (int r = 0; r < 4; r++) {
                int R = r0 + wr * 64 + rb * 16 + quad * 4 + r;
                float v = acc[rb][cb][r];
                if (MODE == 1) {
                    int b = R >> 10, s = R & 1023;
                    int h = C >> 6,  d = C & 63;
                    Cb[(((size_t)b * NHEAD + h) * 1024 + s) * DHEAD + d] =
                        (bf16_t)((v + bias[C]) * scale);
                } else {
                    Cb[((size_t)(C >> 10) * 1024 + R) * 1024 + (C & 1023)] =
                        (bf16_t)(v + bias[R]);
                }
            }
        }
    }
}

// grid (32, 8, 3): x = M-tile (XCD locality: id%8 = x%8), y = N-tile.
__global__ __launch_bounds__(256, 3) void gemm_qkv(
    const bf16_t* __restrict__ Xq, const bf16_t* __restrict__ Xk, const bf16_t* __restrict__ Xv,
    const bf16_t* __restrict__ Wtq, const bf16_t* __restrict__ Wtk, const bf16_t* __restrict__ Wtv,
    const float* __restrict__ bq, const float* __restrict__ bk, const float* __restrict__ bv,
    bf16_t* __restrict__ Qd, bf16_t* __restrict__ Kd, bf16_t* __restrict__ Vt)
{
    __shared__ __align__(16) bf16_t As[3 * 128 * 32];   // 24 KB
    __shared__ __align__(16) bf16_t Bs[3 * 128 * 32];   // 24 KB
    int z = blockIdx.z;
    if (z == 0) {
        gemm_body<1>(Xq, Wtq, bq, QSCALE, Qd,
                     blockIdx.x * 128, blockIdx.y * 128, As, Bs);
    } else if (z == 1) {
        gemm_body<1>(Xk, Wtk, bk, 1.0f, Kd,
                     blockIdx.x * 128, blockIdx.y * 128, As, Bs);
    } else {
        // Vt = (Xv Wv)^T : A = Wtv (8 channel tiles = y), B = Xv (32 token tiles = x)
        gemm_body<2>(Wtv, Xv, bv, 1.0f, Vt,
                     blockIdx.y * 128, blockIdx.x * 128, As, Bs);
    }
}

// ---------------- output projection: 64x128, 3-buffer depth-2 ---------------
__global__ __launch_bounds__(256, 2) void gemm_out(
    const bf16_t* __restrict__ At, const bf16_t* __restrict__ Wto,
    const float* __restrict__ bo, float* __restrict__ out)
{
    const int K = 1024;
    __shared__ __align__(16) bf16_t As[3 * 64 * 32];    // 12 KB
    __shared__ __align__(16) bf16_t Bs[3 * 128 * 32];   // 24 KB

    int tid  = threadIdx.x;
    int wave = tid >> 6;
    int lane = tid & 63;
    int quad = lane >> 4;
    int ln   = lane & 15;

    int r0 = blockIdx.x * 64;
    int c0 = blockIdx.y * 128;

    f32x4 acc[4][2];
    for (int rb = 0; rb < 4; rb++)
        for (int cb = 0; cb < 2; cb++)
            acc[rb][cb] = (f32x4){0.f, 0.f, 0.f, 0.f};

    int sr = tid >> 2;
    int sk = (((tid & 3) ^ ((tid >> 3) & 3))) * 8;

    const bf16_t* gA0 = At  + (size_t)(r0 + sr) * K + sk;
    const bf16_t* gB0 = Wto + (size_t)(c0 + sr) * K + sk;
    const bf16_t* gB1 = gB0 + (size_t)64 * K;
    char* lA = (char*)As + wave * 1024;   // slot stride 4096 B
    char* lB = (char*)Bs + wave * 1024;   // slot stride 8192 B

    int ch = (quad ^ ((ln >> 1) & 3)) * 8;

    auto STAGE = [&](int s, int slot) {
        int k = s * 32;
        gload_lds16(gA0 + k, lA + slot * 4096);
        gload_lds16(gB0 + k, lB + slot * 8192);
        gload_lds16(gB1 + k, lB + slot * 8192 + 4096);
    };
    auto COMPUTE = [&](int slot) {
        const bf16_t* Ab = As + slot * 2048;
        const bf16_t* Bb = Bs + slot * 4096;
        bf16x8 af[4], bfv[2];
        #pragma unroll
        for (int rb = 0; rb < 4; rb++)
            af[rb] = *(const bf16x8*)&Ab[(rb * 16 + ln) * 32 + ch];
        #pragma unroll
        for (int cb = 0; cb < 2; cb++)
            bfv[cb] = *(const bf16x8*)&Bb[(wave * 32 + cb * 16 + ln) * 32 + ch];
        __builtin_amdgcn_s_setprio(1);
        #pragma unroll
        for (int rb = 0; rb < 4; rb++)
            #pragma unroll
            for (int cb = 0; cb < 2; cb++)
                acc[rb][cb] = __builtin_amdgcn_mfma_f32_16x16x32_bf16(af[rb], bfv[cb], acc[rb][cb], 0, 0, 0);
        __builtin_amdgcn_s_setprio(0);
    };

    STAGE(0, 0); STAGE(1, 1);
    WAITVM(3);
    BAR();

    for (int tt = 0; tt < 30; tt += 3) {
        STAGE(tt + 2, 2); COMPUTE(0); WAITVM(3); BAR();
        STAGE(tt + 3, 0); COMPUTE(1); WAITVM(3); BAR();
        STAGE(tt + 4, 1); COMPUTE(2); WAITVM(3); BAR();
    }
    COMPUTE(0); WAITVM(0); BAR();
    COMPUTE(1);

    for (int rb = 0; rb < 4; rb++) {
        for (int cb = 0; cb < 2; cb++) {
            int C = c0 + wave * 32 + cb * 16 + ln;
            float bn = bo[C];
            for (int r = 0; r < 4; r++) {
                int R = r0 + rb * 16 + quad * 4 + r;
                out[(size_t)R * DM + C] = acc[rb][cb][r] + bn;
            }
        }
    }
}

// ---------------- flash attention: K/V LDS dbuf, 1 barrier/kt ---------------
// Q,K: [bh][s][64] bf16 (Q pre-scaled by QSCALE -> exp2 domain).  Vt: [bh][d][s].
// grid (64, 8): x = bh (XCD locality), y = q-tile(128 rows, 32/wave).
// Raw s_barrier with lgkmcnt(0) only (publishes ds_writes) -- the vmcnt
// prefetch of kt+2's K/V registers stays in flight across the barrier
// (__syncthreads would drain it). One barrier per kt instead of two.
__global__ __launch_bounds__(256) void attn7(
    const bf16_t* __restrict__ Q,
    const bf16_t* __restrict__ K,
    const bf16_t* __restrict__ Vt,
    bf16_t* __restrict__ O)
{
    __shared__ __align__(16) bf16_t Ks[2][64 * RS];
    __shared__ __align__(16) bf16_t Vs[2][64 * RS];
    __shared__ __align__(16) bf16_t Ps[4][32 * RS];

    int tid  = threadIdx.x;
    int wave = tid >> 6;
    int lane = tid & 63;
    int quad = lane >> 4;
    int ln   = lane & 15;

    int bh = blockIdx.x;
    int q0w = blockIdx.y * 128 + wave * 32;

    const bf16_t* Qb = Q  + (size_t)bh * 65536;
    const bf16_t* Kb = K  + (size_t)bh * 65536;
    const bf16_t* Vb = Vt + (size_t)bh * 65536;

    int srow = tid >> 3;
    int scol = (tid & 7) * 8;
    const bf16_t* gK0 = Kb + (size_t)srow * 64 + scol;
    const bf16_t* gK1 = gK0 + 32 * 64;
    const bf16_t* gV0 = Vb + (size_t)srow * 1024 + scol;
    const bf16_t* gV1 = gV0 + 32 * 1024;

    bf16x8 aq0[2], aq1[2];
    for (int h = 0; h < 2; h++) {
        aq0[h] = *(const bf16x8*)&Qb[(size_t)(q0w + h * 16 + ln) * 64 + quad * 8];
        aq1[h] = *(const bf16x8*)&Qb[(size_t)(q0w + h * 16 + ln) * 64 + 32 + quad * 8];
    }

    // prologue: kt=0 -> buf0; prefetch kt=1 into regs
    uint4 rK0 = *(const uint4*)gK0;
    uint4 rK1 = *(const uint4*)gK1;
    uint4 rV0 = *(const uint4*)gV0;
    uint4 rV1 = *(const uint4*)gV1;
    *(uint4*)&Ks[0][srow * RS + scol]        = rK0;
    *(uint4*)&Ks[0][(32 + srow) * RS + scol] = rK1;
    *(uint4*)&Vs[0][srow * RS + scol]        = rV0;
    *(uint4*)&Vs[0][(32 + srow) * RS + scol] = rV1;
    gK0 += 4096; gK1 += 4096; gV0 += 64; gV1 += 64;
    rK0 = *(const uint4*)gK0;
    rK1 = *(const uint4*)gK1;
    rV0 = *(const uint4*)gV0;
    rV1 = *(const uint4*)gV1;

    float l_lane[2] = {0.f, 0.f};
    f32x4 o_acc[2][4];
    for (int h = 0; h < 2; h++)
        for (int cb = 0; cb < 4; cb++)
            o_acc[h][cb] = (f32x4){0.f, 0.f, 0.f, 0.f};

    bf16_t* Pw = Ps[wave];

    LGKM0();
    BAR();

    for (int kt = 0; kt < 16; kt++) {
        const bf16_t* Kc = Ks[kt & 1];
        const bf16_t* Vc = Vs[kt & 1];
        bf16_t* Kn = Ks[(kt + 1) & 1];
        bf16_t* Vn = Vs[(kt + 1) & 1];

        if (kt < 15) {
            // store kt+1 regs into the buffer whose readers (kt-1) are done
            *(uint4*)&Kn[srow * RS + scol]        = rK0;
            *(uint4*)&Kn[(32 + srow) * RS + scol] = rK1;
            *(uint4*)&Vn[srow * RS + scol]        = rV0;
            *(uint4*)&Vn[(32 + srow) * RS + scol] = rV1;
        }
        if (kt < 14) {
            gK0 += 4096; gK1 += 4096; gV0 += 64; gV1 += 64;
            rK0 = *(const uint4*)gK0;
            rK1 = *(const uint4*)gK1;
            rV0 = *(const uint4*)gV0;
            rV1 = *(const uint4*)gV1;
        }

        // ---- S^T = K Q^T (two 16-row q-halves share K fragments) ----
        f32x4 sc[4][2];
        for (int kb = 0; kb < 4; kb++) {
            bf16x8 kf0 = *(const bf16x8*)&Kc[(kb * 16 + ln) * RS + quad * 8];
            bf16x8 kf1 = *(const bf16x8*)&Kc[(kb * 16 + ln) * RS + 32 + quad * 8];
            for (int h = 0; h < 2; h++) {
                f32x4 a = (f32x4){0.f, 0.f, 0.f, 0.f};
                a = __builtin_amdgcn_mfma_f32_16x16x32_bf16(kf0, aq0[h], a, 0, 0, 0);
                a = __builtin_amdgcn_mfma_f32_16x16x32_bf16(kf1, aq1[h], a, 0, 0, 0);
                sc[kb][h] = a;
            }
        }

        // ---- P = exp2(sc - PSHIFT) ----
        for (int kb = 0; kb < 4; kb++) {
            for (int h = 0; h < 2; h++) {
                float p0 = __builtin_amdgcn_exp2f(sc[kb][h][0] - PSHIFT);
                float p1 = __builtin_amdgcn_exp2f(sc[kb][h][1] - PSHIFT);
                float p2 = __builtin_amdgcn_exp2f(sc[kb][h][2] - PSHIFT);
                float p3 = __builtin_amdgcn_exp2f(sc[kb][h][3] - PSHIFT);
                l_lane[h] += (p0 + p1) + (p2 + p3);
                bf16x4 pk = (bf16x4){(bf16_t)p0, (bf16_t)p1, (bf16_t)p2, (bf16_t)p3};
                *(bf16x4*)&Pw[(h * 16 + ln) * RS + kb * 16 + quad * 4] = pk;
            }
        }

        // ---- O += P V (V fragments shared across q-halves) ----
        for (int kc = 0; kc < 2; kc++) {
            bf16x8 ap0 = *(const bf16x8*)&Pw[ln * RS + kc * 32 + quad * 8];
            bf16x8 ap1 = *(const bf16x8*)&Pw[(16 + ln) * RS + kc * 32 + quad * 8];
            for (int cb = 0; cb < 4; cb++) {
                bf16x8 vf = *(const bf16x8*)&Vc[(cb * 16 + ln) * RS + kc * 32 + quad * 8];
                o_acc[0][cb] = __builtin_amdgcn_mfma_f32_16x16x32_bf16(ap0, vf, o_acc[0][cb], 0, 0, 0);
                o_acc[1][cb] = __builtin_amdgcn_mfma_f32_16x16x32_bf16(ap1, vf, o_acc[1][cb], 0, 0, 0);
            }
        }

        if (kt < 15) {
            LGKM0();   // publish kt+1 stores (reads already drained by MFMA deps)
            BAR();     // vmcnt prefetch stays in flight
        }
    }

    int b = bh >> 4, hd = bh & 15;
    for (int h = 0; h < 2; h++) {
        float l = l_lane[h];
        l += __shfl_xor(l, 16);
        l += __shfl_xor(l, 32);
        float invq[4];
        for (int r = 0; r < 4; r++)
            invq[r] = 1.f / __shfl(l, quad * 4 + r);
        for (int cb = 0; cb < 4; cb++) {
            for (int r = 0; r < 4; r++) {
                int q = q0w + h * 16 + quad * 4 + r;
                int d = cb * 16 + ln;
                O[((size_t)b * 1024 + q) * DM + hd * 64 + d] = (bf16_t)(o_acc[h][cb][r] * invq[r]);
            }
        }
    }
}

extern "C" void kernel_launch(void* const* d_in, const int* in_sizes, int n_in,
                              void* d_out, int out_size, void* d_ws, size_t ws_size,
                              hipStream_t stream) {
    const float* q_in = (const float*)d_in[0];
    const float* k_in = (const float*)d_in[1];
    const float* v_in = (const float*)d_in[2];
    const float* Wq   = (const float*)d_in[3];
    const float* bq   = (const float*)d_in[4];
    const float* Wk   = (const float*)d_in[5];
    const float* bk   = (const float*)d_in[6];
    const float* Wv   = (const float*)d_in[7];
    const float* bv   = (const float*)d_in[8];
    const float* Wo   = (const float*)d_in[9];
    const float* bo   = (const float*)d_in[10];

    char* ws = (char*)d_ws;
    const size_t MB = 1024ull * 1024ull;
    bf16_t* Xq  = (bf16_t*)(ws);             // 8 MB
    bf16_t* Xk  = (bf16_t*)(ws + 8 * MB);
    bf16_t* Xv  = (bf16_t*)(ws + 16 * MB);
    bf16_t* Wtq = (bf16_t*)(ws + 24 * MB);
    bf16_t* Wtk = (bf16_t*)(ws + 26 * MB);
    bf16_t* Wtv = (bf16_t*)(ws + 28 * MB);
    bf16_t* Wto = (bf16_t*)(ws + 30 * MB);
    bf16_t* Qd  = (bf16_t*)(ws + 32 * MB);   // [bh][s][d]
    bf16_t* Kd  = (bf16_t*)(ws + 40 * MB);   // [bh][s][d]
    bf16_t* Vt  = (bf16_t*)(ws + 48 * MB);   // [bh][d][s]
    bf16_t* At  = Xq;                        // attn out aliases Xq (dead by then)

    prep<<<7168, 256, 0, stream>>>(q_in, k_in, v_in, Xq, Xk, Xv,
                                   Wq, Wk, Wv, Wo, Wtq, Wtk, Wtv, Wto);

    gemm_qkv<<<dim3(32, 8, 3), 256, 0, stream>>>(Xq, Xk, Xv,
                                                 Wtq, Wtk, Wtv, bq, bk, bv, Qd, Kd, Vt);

    attn7<<<dim3(64, 8), 256, 0, stream>>>(Qd, Kd, Vt, At);

    gemm_out<<<dim3(64, 8), 256, 0, stream>>>(At, Wto, bo, (float*)d_out);
}